// Round 11
// baseline (254.264 us; speedup 1.0000x reference)
//
#include <hip/hip_runtime.h>
#include <hip/hip_fp16.h>

#define JN 17

typedef __fp16 h2v __attribute__((ext_vector_type(2)));
typedef _Float16 f16x8 __attribute__((ext_vector_type(8)));
typedef float f32x4 __attribute__((ext_vector_type(4)));

__device__ __forceinline__ float lrelu(float x){ return fmaxf(x, 0.01f*x); }
__device__ __forceinline__ unsigned h2u(h2v h){ unsigned u; __builtin_memcpy(&u, &h, 4); return u; }
__device__ __forceinline__ h2v u2h(unsigned u){ h2v h; __builtin_memcpy(&h, &u, 4); return h; }
__device__ __forceinline__ unsigned pkrtz(float a, float b){ return h2u(__builtin_amdgcn_cvt_pkrtz(a,b)); }
__device__ __forceinline__ float fdot2(unsigned a, unsigned b, float c){
    return __builtin_amdgcn_fdot2(u2h(a), u2h(b), c, false);
}
__device__ __forceinline__ unsigned pkfma(unsigned a, unsigned b, unsigned c){
    h2v r = u2h(a)*u2h(b) + u2h(c);
    return h2u(r);
}
__device__ __forceinline__ f16x8 u4h8(uint4 u){ union{uint4 u; f16x8 h;} c; c.u=u; return c.h; }
__device__ __forceinline__ f32x4 mk4(float4 v){ f32x4 r; r[0]=v.x; r[1]=v.y; r[2]=v.z; r[3]=v.w; return r; }

// C(t0,t1) -> B-frag of next MFMA via cross-lane permute (values post-activation).
__device__ __forceinline__ f16x8 repack(f32x4 c0, f32x4 c1, int srcA, int srcB, bool selLo){
    unsigned pkA = pkrtz(c0[0], c0[1]);
    unsigned pkB = pkrtz(c0[2], c0[3]);
    unsigned pkC = pkrtz(c1[0], c1[1]);
    unsigned pkD = pkrtz(c1[2], c1[3]);
    unsigned rA0 = (unsigned)__shfl((int)pkA, srcA, 64);
    unsigned rB0 = (unsigned)__shfl((int)pkB, srcA, 64);
    unsigned rC0 = (unsigned)__shfl((int)pkC, srcA, 64);
    unsigned rD0 = (unsigned)__shfl((int)pkD, srcA, 64);
    unsigned rA1 = (unsigned)__shfl((int)pkA, srcB, 64);
    unsigned rB1 = (unsigned)__shfl((int)pkB, srcB, 64);
    unsigned rC1 = (unsigned)__shfl((int)pkC, srcB, 64);
    unsigned rD1 = (unsigned)__shfl((int)pkD, srcB, 64);
    uint4 u;
    u.x = selLo ? rA0 : rC0;
    u.y = selLo ? rB0 : rD0;
    u.z = selLo ? rA1 : rC1;
    u.w = selLo ? rB1 : rD1;
    return u4h8(u);
}

// ws header layout (u32 units), first 65536 bytes
#define OFF_PP    0
#define OFF_BQS   544
#define OFF_FQ    576
#define OFF_WD1I  1088
#define OFF_WD2   1600
#define OFF_FUD   2112
#define OFF_FK    2624
#define OFF_FV    3136
#define OFF_TUP   3648
#define OFF_FUP   4192
#define HDR_BYTES 65536

#define KSTRIDE 276
#define QSTRIDE 132

// ---------------- prep ------------------------------------------------------
__global__ __launch_bounds__(256,1)
void prep_kernel(const void* __restrict__ mraw, const float* __restrict__ pos,
                 const float* __restrict__ Wup,
                 const float* __restrict__ Wud, const float* __restrict__ bud,
                 const float* __restrict__ Wq,  const float* __restrict__ bq,
                 const float* __restrict__ Wk,  const float* __restrict__ Wv,
                 const float* __restrict__ Wd1, const float* __restrict__ Wd2,
                 unsigned* __restrict__ ws32, unsigned* __restrict__ bmask, int B)
{
    int g = blockIdx.x*256 + threadIdx.x;
    const float isq = 0.17677669529663687f;

    const unsigned* mw = (const unsigned*)mraw;
    bool f3f=false, nz=false;
    #pragma unroll
    for (int i=0;i<17;i++){
        unsigned w = mw[i];
        if ((w>>24) == 0x3Fu) f3f = true;
        if (w & 0xFFFFFF00u)  nz  = true;
    }
    int mode = f3f ? 2 : (nz ? 1 : 0);
    if (g < B){
        unsigned bm = 0; size_t base = (size_t)g*JN;
        if (mode == 0){
            const int* mi = (const int*)mraw;
            #pragma unroll
            for (int j=0;j<JN;j++) if (mi[base+j] != 0) bm |= (1u<<j);
        } else if (mode == 1){
            const unsigned char* mb = (const unsigned char*)mraw;
            #pragma unroll
            for (int j=0;j<JN;j++) if (mb[base+j] != 0) bm |= (1u<<j);
        } else {
            const float* mf = (const float*)mraw;
            #pragma unroll
            for (int j=0;j<JN;j++) if (mf[base+j] != 0.f) bm |= (1u<<j);
        }
        bmask[g] = bm;
    }
    if (g < 544){
        int j = g >> 5, h = g & 31;
        float acc = bud[h];
        #pragma unroll
        for (int c=0;c<32;c++) acc = fmaf(pos[j*32+c], Wud[(32+c)*32 + h], acc);
        ((float*)ws32)[OFF_PP + g] = acc;
        int t = (g >> 4) & 1, c = g & 15;
        int col = j*32 + t*16 + c;
        ws32[OFF_TUP + g] = pkrtz(Wup[32*544 + col], Wup[33*544 + col]);
    }
    if (g < 32) ((float*)ws32)[OFF_BQS + g] = bq[g]*isq;
    if (g < 512){
        int t = g >> 8, rmn = g & 255, lane = rmn >> 2, i2 = rmn & 3;
        int k0 = (lane>>4)*8 + 2*i2, c = (lane&15) + 16*t;
        ws32[OFF_FUD + g] = pkrtz(Wud[k0*32 + c],     Wud[(k0+1)*32 + c]);
        ws32[OFF_FK  + g] = pkrtz(Wk [k0*32 + c],     Wk [(k0+1)*32 + c]);
        ws32[OFF_FV  + g] = pkrtz(Wv [k0*32 + c],     Wv [(k0+1)*32 + c]);
        ws32[OFF_FQ  + g] = pkrtz(Wq [k0*32 + c]*isq, Wq [(k0+1)*32 + c]*isq);
        int p = g >> 5, h = g & 31;
        ws32[OFF_WD1I + g] = pkrtz(Wd1[p*32+h],     Wd1[(p+16)*32+h]);
        ws32[OFF_WD2  + g] = pkrtz(Wd2[(2*p)*32+h], Wd2[(2*p+1)*32+h]);
    }
    if (g < 8704){
        int j = g >> 9, r = g & 511, t = r >> 8, rr = r & 255, lane = rr >> 2, i2 = rr & 3;
        int k0 = (lane>>4)*8 + 2*i2;
        int col = j*32 + (lane&15) + 16*t;
        ws32[OFF_FUP + g] = pkrtz(Wup[k0*544 + col], Wup[(k0+1)*544 + col]);
    }
}

// ---------------- fused kernel: 16 samples / block (4 waves) -----------------
// Phase1 (transposed MFMA), results to LDS. Phase2: 256 lanes = 128 (s,q) pairs
// x 2 lanes (lane-pair split; partner = tid^1).
__global__ __launch_bounds__(256,3)
void fused_kernel(const float* __restrict__ x, const unsigned* __restrict__ bmask,
                  const unsigned* __restrict__ ws32,
                  const float* __restrict__ bup, const float* __restrict__ bk,
                  const float* __restrict__ bv,  const float* __restrict__ bd1,
                  const float* __restrict__ bd2, const float* __restrict__ Ws,
                  const float* __restrict__ bs,  float* __restrict__ out, int B)
{
    __shared__ unsigned ksl[16*KSTRIDE];
    __shared__ unsigned vsl[16*KSTRIDE];
    __shared__ unsigned qsl[16*QSTRIDE];
    __shared__ unsigned usl[16*QSTRIDE];

    const int tid = threadIdx.x;
    const int wid = tid >> 6, wl = tid & 63;
    const int sb  = blockIdx.x * 16;
    const int s   = wl & 15, g4 = wl >> 4;
    const int smax = B - 1;

    // ---------------- phase 1 ----------------
    {
        int sA = sb + s; if (sA > smax) sA = smax;
        f16x8 ax;
        {
            const float* xr = x + (size_t)sA*34 + g4*8;
            float2 a0 = *(const float2*)(xr);
            float2 a1 = *(const float2*)(xr+2);
            float2 a2 = *(const float2*)(xr+4);
            float2 a3 = *(const float2*)(xr+6);
            uint4 u; u.x=pkrtz(a0.x,a0.y); u.y=pkrtz(a1.x,a1.y);
            u.z=pkrtz(a2.x,a2.y); u.w=pkrtz(a3.x,a3.y);
            ax = u4h8(u);
        }
        const unsigned bm = bmask[sA];
        float2 xt2 = *(const float2*)(x + (size_t)sA*34 + 32);
        const unsigned xtp = pkrtz(xt2.x, xt2.y);

        const uint4* wsu4 = (const uint4*)ws32;
        f16x8 fud0 = u4h8(wsu4[OFF_FUD/4 + wl]);
        f16x8 fud1 = u4h8(wsu4[OFF_FUD/4 + 64 + wl]);
        f16x8 fk0  = u4h8(wsu4[OFF_FK/4  + wl]);
        f16x8 fk1  = u4h8(wsu4[OFF_FK/4  + 64 + wl]);
        f16x8 fv0  = u4h8(wsu4[OFF_FV/4  + wl]);
        f16x8 fv1  = u4h8(wsu4[OFF_FV/4  + 64 + wl]);
        f16x8 fq0  = u4h8(wsu4[OFF_FQ/4  + wl]);
        f16x8 fq1  = u4h8(wsu4[OFF_FQ/4  + 64 + wl]);

        const float* ppf = (const float*)ws32;
        float4 bk0 = *(const float4*)(bk + g4*4);
        float4 bk1 = *(const float4*)(bk + 16 + g4*4);
        float4 bv0 = *(const float4*)(bv + g4*4);
        float4 bv1 = *(const float4*)(bv + 16 + g4*4);
        float4 bq0 = *(const float4*)(ppf + OFF_BQS + g4*4);
        float4 bq1 = *(const float4*)(ppf + OFF_BQS + 16 + g4*4);

        const int srcA = s + 32*(g4 & 1);
        const int srcB = srcA + 16;
        const bool selLo = (g4 < 2);

        const int njl = (wid == 3) ? 5 : 4;
        for (int jj = 0; jj < njl; jj++){
            const int j = (jj < 4) ? (wid + jj*4) : 16;
            f16x8 fup0 = u4h8(wsu4[OFF_FUP/4 + j*128 + wl]);
            f16x8 fup1 = u4h8(wsu4[OFF_FUP/4 + j*128 + 64 + wl]);
            float4 bu0 = *(const float4*)(bup + j*32 + g4*4);
            float4 bu1 = *(const float4*)(bup + j*32 + 16 + g4*4);
            float4 pp0 = *(const float4*)(ppf + OFF_PP + j*32 + g4*4);
            float4 pp1 = *(const float4*)(ppf + OFF_PP + j*32 + 16 + g4*4);
            uint4 tu0 = *(const uint4*)(ws32 + OFF_TUP + j*32 + g4*4);
            uint4 tu1 = *(const uint4*)(ws32 + OFF_TUP + j*32 + 16 + g4*4);

            f32x4 up0, up1;
            up0[0] = fdot2(xtp, tu0.x, bu0.x); up0[1] = fdot2(xtp, tu0.y, bu0.y);
            up0[2] = fdot2(xtp, tu0.z, bu0.z); up0[3] = fdot2(xtp, tu0.w, bu0.w);
            up1[0] = fdot2(xtp, tu1.x, bu1.x); up1[1] = fdot2(xtp, tu1.y, bu1.y);
            up1[2] = fdot2(xtp, tu1.z, bu1.z); up1[3] = fdot2(xtp, tu1.w, bu1.w);
            up0 = __builtin_amdgcn_mfma_f32_16x16x32_f16(fup0, ax, up0, 0,0,0);
            up1 = __builtin_amdgcn_mfma_f32_16x16x32_f16(fup1, ax, up1, 0,0,0);
            #pragma unroll
            for (int r=0;r<4;r++){ up0[r] = lrelu(up0[r]); up1[r] = lrelu(up1[r]); }

            const bool occ = !((bm>>j)&1u);
            const int rk = __popc((~bm) & ((1u<<j)-1u));
            if (occ){
                int rotq = (rk + s + (s>>2)) & 3;
                uint4 u;
                u.x = pkrtz(up0[0], up1[0]); u.y = pkrtz(up0[1], up1[1]);
                u.z = pkrtz(up0[2], up1[2]); u.w = pkrtz(up0[3], up1[3]);
                *(uint4*)&usl[s*QSTRIDE + rk*16 + ((g4 + rotq)&3)*4] = u;
            }
            f16x8 aup = repack(up0, up1, srcA, srcB, selLo);

            f32x4 uu0 = mk4(pp0), uu1 = mk4(pp1);
            uu0 = __builtin_amdgcn_mfma_f32_16x16x32_f16(fud0, aup, uu0, 0,0,0);
            uu1 = __builtin_amdgcn_mfma_f32_16x16x32_f16(fud1, aup, uu1, 0,0,0);
            #pragma unroll
            for (int r=0;r<4;r++){ uu0[r] = lrelu(uu0[r]); uu1[r] = lrelu(uu1[r]); }
            f16x8 auu = repack(uu0, uu1, srcA, srcB, selLo);

            f32x4 kk0 = mk4(bk0), kk1 = mk4(bk1);
            f32x4 vv0 = mk4(bv0), vv1 = mk4(bv1);
            f32x4 qq0 = mk4(bq0), qq1 = mk4(bq1);
            kk0 = __builtin_amdgcn_mfma_f32_16x16x32_f16(fk0, auu, kk0, 0,0,0);
            kk1 = __builtin_amdgcn_mfma_f32_16x16x32_f16(fk1, auu, kk1, 0,0,0);
            vv0 = __builtin_amdgcn_mfma_f32_16x16x32_f16(fv0, auu, vv0, 0,0,0);
            vv1 = __builtin_amdgcn_mfma_f32_16x16x32_f16(fv1, auu, vv1, 0,0,0);
            qq0 = __builtin_amdgcn_mfma_f32_16x16x32_f16(fq0, auu, qq0, 0,0,0);
            qq1 = __builtin_amdgcn_mfma_f32_16x16x32_f16(fq1, auu, qq1, 0,0,0);

            const int rot = (j + s + (s>>2)) & 3;
            const int grp = ((g4 + rot)&3)*4;
            uint4 kp, vp;
            kp.x = pkrtz(kk0[0], kk1[0]); kp.y = pkrtz(kk0[1], kk1[1]);
            kp.z = pkrtz(kk0[2], kk1[2]); kp.w = pkrtz(kk0[3], kk1[3]);
            vp.x = pkrtz(vv0[0], vv1[0]); vp.y = pkrtz(vv0[1], vv1[1]);
            vp.z = pkrtz(vv0[2], vv1[2]); vp.w = pkrtz(vv0[3], vv1[3]);
            *(uint4*)&ksl[s*KSTRIDE + j*16 + grp] = kp;
            *(uint4*)&vsl[s*KSTRIDE + j*16 + grp] = vp;
            if (occ){
                int rotq = (rk + s + (s>>2)) & 3;
                uint4 qp4;
                qp4.x = pkrtz(qq0[0], qq1[0]); qp4.y = pkrtz(qq0[1], qq1[1]);
                qp4.z = pkrtz(qq0[2], qq1[2]); qp4.w = pkrtz(qq0[3], qq1[3]);
                *(uint4*)&qsl[s*QSTRIDE + rk*16 + ((g4 + rotq)&3)*4] = qp4;
            }
        }
    }
    __syncthreads();

    // ---------------- phase 2: 128 pairs x 2 lanes ----------------
    const int c  = tid & 1;           // half id; partner = tid^1 (same wave)
    const int pr = tid >> 1;          // pair id 0..127
    const int s2 = pr >> 3, q = pr & 7;
    if (sb + s2 >= B) return;

    // q row (both lanes full)
    unsigned qw[16];
    {
        int rot = (q + s2 + (s2>>2)) & 3;
        const unsigned* base = qsl + s2*QSTRIDE + q*16;
        #pragma unroll
        for (int a=0;a<4;a++){
            uint4 t = *(const uint4*)(base + ((a + rot)&3)*4);
            qw[4*a]=t.x; qw[4*a+1]=t.y; qw[4*a+2]=t.z; qw[4*a+3]=t.w;
        }
    }
    // scores: lane c computes 9 keys starting at c*8 (kj=8 overlaps, harmless)
    float scl[9];
    #pragma unroll
    for (int i=0;i<9;i++){
        int kj = c*8 + i;
        unsigned kw[16];
        int rot = (kj + s2 + (s2>>2)) & 3;
        const unsigned* base = ksl + s2*KSTRIDE + kj*16;
        #pragma unroll
        for (int a=0;a<4;a++){
            uint4 t = *(const uint4*)(base + ((a + rot)&3)*4);
            kw[4*a]=t.x; kw[4*a+1]=t.y; kw[4*a+2]=t.z; kw[4*a+3]=t.w;
        }
        float s0=0.f,s1=0.f,s2a=0.f,s3=0.f;
        #pragma unroll
        for (int p=0;p<16;p+=4){
            s0  = fdot2(qw[p],   kw[p],   s0);
            s1  = fdot2(qw[p+1], kw[p+1], s1);
            s2a = fdot2(qw[p+2], kw[p+2], s2a);
            s3  = fdot2(qw[p+3], kw[p+3], s3);
        }
        scl[i] = (s0+s1)+(s2a+s3);
    }
    // exchange: full 17-score row on both lanes (own base c*8, partner (1-c)*8)
    float sc[JN];
    #pragma unroll
    for (int i=0;i<9;i++){
        float r = __shfl_xor(scl[i], 1, 64);
        sc[c*8 + i] = scl[i];
        sc[(1-c)*8 + i] = r;
    }
    float m = sc[0];
    #pragma unroll
    for (int kj=1;kj<JN;kj++) m = fmaxf(m, sc[kj]);
    float e[JN]; float sum = 0.f;
    #pragma unroll
    for (int kj=0;kj<JN;kj++){ e[kj] = __expf(sc[kj]-m); sum += e[kj]; }
    float ri = 1.0f/sum;

    // PV: h-half split — lane c owns v dwords p = c*8..c*8+7 (groups a=2c,2c+1)
    unsigned o[8];
    #pragma unroll
    for (int i=0;i<8;i++) o[i] = 0u;
    #pragma unroll
    for (int kj=0;kj<JN;kj++){
        float w = e[kj]*ri;
        unsigned w2 = pkrtz(w, w);
        int rot = (kj + s2 + (s2>>2)) & 3;
        const unsigned* base = vsl + s2*KSTRIDE + kj*16;
        uint4 t0 = *(const uint4*)(base + ((2*c   + rot)&3)*4);
        uint4 t1 = *(const uint4*)(base + ((2*c+1 + rot)&3)*4);
        unsigned vw[8] = {t0.x,t0.y,t0.z,t0.w,t1.x,t1.y,t1.z,t1.w};
        #pragma unroll
        for (int i=0;i<8;i++) o[i] = pkfma(w2, vw[i], o[i]);
    }

    // d1 partial: p = c*8+i; t combined via f32 exchange
    const unsigned* wd1I = ws32 + OFF_WD1I;
    const unsigned* wd2  = ws32 + OFF_WD2;
    float t[32];
    #pragma unroll
    for (int h=0;h<32;h++) t[h] = c ? 0.f : bd1[h];
    #pragma unroll
    for (int i=0;i<8;i++){
        unsigned a = o[i];
        int p = c*8 + i;
        #pragma unroll
        for (int h=0;h<32;h++) t[h] = fdot2(a, wd1I[p*32+h], t[h]);
    }
    #pragma unroll
    for (int h=0;h<32;h++) t[h] += __shfl_xor(t[h], 1, 64);
    unsigned tp[16];
    #pragma unroll
    for (int p=0;p<16;p++) tp[p] = pkrtz(lrelu(t[2*p]), lrelu(t[2*p+1]));

    // d2 partial: z init on own half (residual + bd2), accumulate own 8 tp's
    float z[32];
    #pragma unroll
    for (int h=0;h<32;h++) z[h] = 0.f;
    {
        int rot = (q + s2 + (s2>>2)) & 3;
        const unsigned* base = usl + s2*QSTRIDE + q*16;
        #pragma unroll
        for (int aa=0;aa<2;aa++){
            int a = 2*c + aa;
            uint4 tt = *(const uint4*)(base + ((a + rot)&3)*4);
            unsigned pw[4] = {tt.x, tt.y, tt.z, tt.w};
            #pragma unroll
            for (int i=0;i<4;i++){
                int p = 4*a + i;
                h2v r = u2h(pw[i]);
                z[p]    = bd2[p]    + (float)r.x;
                z[p+16] = bd2[p+16] + (float)r.y;
            }
        }
    }
    #pragma unroll
    for (int i=0;i<8;i++){
        int p = c*8 + i;
        unsigned a = tp[p];
        #pragma unroll
        for (int h=0;h<32;h++) z[h] = fdot2(a, wd2[p*32+h], z[h]);
    }

    // y = (z_self + z_partner) . Ws : dot partials fully, combine scalar
    float y0=0.f, y1=0.f;
    #pragma unroll
    for (int h=0;h<32;h+=2){ y0 = fmaf(z[h], Ws[h], y0); y1 = fmaf(z[h+1], Ws[h+1], y1); }
    float yp = y0 + y1;
    yp += __shfl_xor(yp, 1, 64);
    if (c == 0){
        float y = yp + bs[0];
        out[((size_t)(sb + s2))*8 + q] = 1.0f/(1.0f + __expf(-y));
    }
}

extern "C" void kernel_launch(void* const* d_in, const int* in_sizes, int n_in,
                              void* d_out, int out_size, void* d_ws, size_t ws_size,
                              hipStream_t stream) {
    (void)n_in; (void)out_size; (void)ws_size;
    const float* x   = (const float*)d_in[0];
    const void*  m   = d_in[1];
    const float* pos = (const float*)d_in[2];
    const float* Wup = (const float*)d_in[3];  const float* bup = (const float*)d_in[4];
    const float* Wud = (const float*)d_in[5];  const float* bud = (const float*)d_in[6];
    const float* Wq  = (const float*)d_in[7];  const float* bq  = (const float*)d_in[8];
    const float* Wk  = (const float*)d_in[9];  const float* bk  = (const float*)d_in[10];
    const float* Wv  = (const float*)d_in[11]; const float* bv  = (const float*)d_in[12];
    const float* Wd1 = (const float*)d_in[13]; const float* bd1 = (const float*)d_in[14];
    const float* Wd2 = (const float*)d_in[15]; const float* bd2 = (const float*)d_in[16];
    const float* Ws  = (const float*)d_in[17]; const float* bs  = (const float*)d_in[18];
    float* out = (float*)d_out;
    int B = in_sizes[0] / (JN*2);

    unsigned char* wsb = (unsigned char*)d_ws;
    unsigned* ws32  = (unsigned*)wsb;
    unsigned* bmask = (unsigned*)(wsb + HDR_BYTES);

    prep_kernel<<<(B+255)/256, 256, 0, stream>>>(m, pos, Wup, Wud, bud, Wq, bq,
                                                 Wk, Wv, Wd1, Wd2, ws32, bmask, B);
    fused_kernel<<<(B+15)/16, 256, 0, stream>>>(x, bmask, ws32, bup, bk, bv,
                                                bd1, bd2, Ws, bs, out, B);
}

// Round 12
// 138.082 us; speedup vs baseline: 1.8414x; 1.8414x over previous
//
#include <hip/hip_runtime.h>
#include <hip/hip_fp16.h>

#define JN 17

typedef __fp16 h2v __attribute__((ext_vector_type(2)));
typedef _Float16 f16x8 __attribute__((ext_vector_type(8)));
typedef float f32x4 __attribute__((ext_vector_type(4)));

__device__ __forceinline__ float lrelu(float x){ return fmaxf(x, 0.01f*x); }
__device__ __forceinline__ unsigned h2u(h2v h){ unsigned u; __builtin_memcpy(&u, &h, 4); return u; }
__device__ __forceinline__ h2v u2h(unsigned u){ h2v h; __builtin_memcpy(&h, &u, 4); return h; }
__device__ __forceinline__ unsigned pkrtz(float a, float b){ return h2u(__builtin_amdgcn_cvt_pkrtz(a,b)); }
__device__ __forceinline__ float fdot2(unsigned a, unsigned b, float c){
    return __builtin_amdgcn_fdot2(u2h(a), u2h(b), c, false);
}
__device__ __forceinline__ unsigned pkfma(unsigned a, unsigned b, unsigned c){
    h2v r = u2h(a)*u2h(b) + u2h(c);
    return h2u(r);
}
__device__ __forceinline__ f16x8 u4h8(uint4 u){ union{uint4 u; f16x8 h;} c; c.u=u; return c.h; }
__device__ __forceinline__ f32x4 mk4(float4 v){ f32x4 r; r[0]=v.x; r[1]=v.y; r[2]=v.z; r[3]=v.w; return r; }

// C(t0,t1) -> B-frag of next MFMA via cross-lane permute (values post-activation).
__device__ __forceinline__ f16x8 repack(f32x4 c0, f32x4 c1, int srcA, int srcB, bool selLo){
    unsigned pkA = pkrtz(c0[0], c0[1]);
    unsigned pkB = pkrtz(c0[2], c0[3]);
    unsigned pkC = pkrtz(c1[0], c1[1]);
    unsigned pkD = pkrtz(c1[2], c1[3]);
    unsigned rA0 = (unsigned)__shfl((int)pkA, srcA, 64);
    unsigned rB0 = (unsigned)__shfl((int)pkB, srcA, 64);
    unsigned rC0 = (unsigned)__shfl((int)pkC, srcA, 64);
    unsigned rD0 = (unsigned)__shfl((int)pkD, srcA, 64);
    unsigned rA1 = (unsigned)__shfl((int)pkA, srcB, 64);
    unsigned rB1 = (unsigned)__shfl((int)pkB, srcB, 64);
    unsigned rC1 = (unsigned)__shfl((int)pkC, srcB, 64);
    unsigned rD1 = (unsigned)__shfl((int)pkD, srcB, 64);
    uint4 u;
    u.x = selLo ? rA0 : rC0;
    u.y = selLo ? rB0 : rD0;
    u.z = selLo ? rA1 : rC1;
    u.w = selLo ? rB1 : rD1;
    return u4h8(u);
}

// ws header layout (u32 units), first 65536 bytes
#define OFF_PP    0
#define OFF_BQS   544
#define OFF_FQ    576
#define OFF_WD1I  1088
#define OFF_WD2   1600
#define OFF_FUD   2112
#define OFF_FK    2624
#define OFF_FV    3136
#define OFF_TUP   3648
#define OFF_FUP   4192
#define HDR_BYTES 65536

#define KSTRIDE 276
#define QSTRIDE 132

// ---------------- prep ------------------------------------------------------
__global__ __launch_bounds__(256,1)
void prep_kernel(const void* __restrict__ mraw, const float* __restrict__ pos,
                 const float* __restrict__ Wup,
                 const float* __restrict__ Wud, const float* __restrict__ bud,
                 const float* __restrict__ Wq,  const float* __restrict__ bq,
                 const float* __restrict__ Wk,  const float* __restrict__ Wv,
                 const float* __restrict__ Wd1, const float* __restrict__ Wd2,
                 unsigned* __restrict__ ws32, unsigned* __restrict__ bmask, int B)
{
    int g = blockIdx.x*256 + threadIdx.x;
    const float isq = 0.17677669529663687f;

    const unsigned* mw = (const unsigned*)mraw;
    bool f3f=false, nz=false;
    #pragma unroll
    for (int i=0;i<17;i++){
        unsigned w = mw[i];
        if ((w>>24) == 0x3Fu) f3f = true;
        if (w & 0xFFFFFF00u)  nz  = true;
    }
    int mode = f3f ? 2 : (nz ? 1 : 0);
    if (g < B){
        unsigned bm = 0; size_t base = (size_t)g*JN;
        if (mode == 0){
            const int* mi = (const int*)mraw;
            #pragma unroll
            for (int j=0;j<JN;j++) if (mi[base+j] != 0) bm |= (1u<<j);
        } else if (mode == 1){
            const unsigned char* mb = (const unsigned char*)mraw;
            #pragma unroll
            for (int j=0;j<JN;j++) if (mb[base+j] != 0) bm |= (1u<<j);
        } else {
            const float* mf = (const float*)mraw;
            #pragma unroll
            for (int j=0;j<JN;j++) if (mf[base+j] != 0.f) bm |= (1u<<j);
        }
        bmask[g] = bm;
    }
    if (g < 544){
        int j = g >> 5, h = g & 31;
        float acc = bud[h];
        #pragma unroll
        for (int c=0;c<32;c++) acc = fmaf(pos[j*32+c], Wud[(32+c)*32 + h], acc);
        ((float*)ws32)[OFF_PP + g] = acc;
        int t = (g >> 4) & 1, c = g & 15;
        int col = j*32 + t*16 + c;
        ws32[OFF_TUP + g] = pkrtz(Wup[32*544 + col], Wup[33*544 + col]);
    }
    if (g < 32) ((float*)ws32)[OFF_BQS + g] = bq[g]*isq;
    if (g < 512){
        int t = g >> 8, rmn = g & 255, lane = rmn >> 2, i2 = rmn & 3;
        int k0 = (lane>>4)*8 + 2*i2, c = (lane&15) + 16*t;
        ws32[OFF_FUD + g] = pkrtz(Wud[k0*32 + c],     Wud[(k0+1)*32 + c]);
        ws32[OFF_FK  + g] = pkrtz(Wk [k0*32 + c],     Wk [(k0+1)*32 + c]);
        ws32[OFF_FV  + g] = pkrtz(Wv [k0*32 + c],     Wv [(k0+1)*32 + c]);
        ws32[OFF_FQ  + g] = pkrtz(Wq [k0*32 + c]*isq, Wq [(k0+1)*32 + c]*isq);
        int p = g >> 5, h = g & 31;
        ws32[OFF_WD1I + g] = pkrtz(Wd1[p*32+h],     Wd1[(p+16)*32+h]);
        ws32[OFF_WD2  + g] = pkrtz(Wd2[(2*p)*32+h], Wd2[(2*p+1)*32+h]);
    }
    if (g < 8704){
        int j = g >> 9, r = g & 511, t = r >> 8, rr = r & 255, lane = rr >> 2, i2 = rr & 3;
        int k0 = (lane>>4)*8 + 2*i2;
        int col = j*32 + (lane&15) + 16*t;
        ws32[OFF_FUP + g] = pkrtz(Wup[k0*544 + col], Wup[(k0+1)*544 + col]);
    }
}

// ---------------- fused kernel: 16 samples / block (4 waves) -----------------
// Phase1 (transposed MFMA), results to LDS. Phase2: 256 lanes = 128 (s,q) pairs
// x 2 lanes. ALL register-array indices compile-time (rule #20); runtime c only
// in memory addresses and value selects.
__global__ __launch_bounds__(256,3)
void fused_kernel(const float* __restrict__ x, const unsigned* __restrict__ bmask,
                  const unsigned* __restrict__ ws32,
                  const float* __restrict__ bup, const float* __restrict__ bk,
                  const float* __restrict__ bv,  const float* __restrict__ bd1,
                  const float* __restrict__ bd2, const float* __restrict__ Ws,
                  const float* __restrict__ bs,  float* __restrict__ out, int B)
{
    __shared__ unsigned ksl[16*KSTRIDE];
    __shared__ unsigned vsl[16*KSTRIDE];
    __shared__ unsigned qsl[16*QSTRIDE];
    __shared__ unsigned usl[16*QSTRIDE];

    const int tid = threadIdx.x;
    const int wid = tid >> 6, wl = tid & 63;
    const int sb  = blockIdx.x * 16;
    const int s   = wl & 15, g4 = wl >> 4;
    const int smax = B - 1;

    // ---------------- phase 1 (unchanged from round 10) ----------------
    {
        int sA = sb + s; if (sA > smax) sA = smax;
        f16x8 ax;
        {
            const float* xr = x + (size_t)sA*34 + g4*8;
            float2 a0 = *(const float2*)(xr);
            float2 a1 = *(const float2*)(xr+2);
            float2 a2 = *(const float2*)(xr+4);
            float2 a3 = *(const float2*)(xr+6);
            uint4 u; u.x=pkrtz(a0.x,a0.y); u.y=pkrtz(a1.x,a1.y);
            u.z=pkrtz(a2.x,a2.y); u.w=pkrtz(a3.x,a3.y);
            ax = u4h8(u);
        }
        const unsigned bm = bmask[sA];
        float2 xt2 = *(const float2*)(x + (size_t)sA*34 + 32);
        const unsigned xtp = pkrtz(xt2.x, xt2.y);

        const uint4* wsu4 = (const uint4*)ws32;
        f16x8 fud0 = u4h8(wsu4[OFF_FUD/4 + wl]);
        f16x8 fud1 = u4h8(wsu4[OFF_FUD/4 + 64 + wl]);
        f16x8 fk0  = u4h8(wsu4[OFF_FK/4  + wl]);
        f16x8 fk1  = u4h8(wsu4[OFF_FK/4  + 64 + wl]);
        f16x8 fv0  = u4h8(wsu4[OFF_FV/4  + wl]);
        f16x8 fv1  = u4h8(wsu4[OFF_FV/4  + 64 + wl]);
        f16x8 fq0  = u4h8(wsu4[OFF_FQ/4  + wl]);
        f16x8 fq1  = u4h8(wsu4[OFF_FQ/4  + 64 + wl]);

        const float* ppf = (const float*)ws32;
        float4 bk0 = *(const float4*)(bk + g4*4);
        float4 bk1 = *(const float4*)(bk + 16 + g4*4);
        float4 bv0 = *(const float4*)(bv + g4*4);
        float4 bv1 = *(const float4*)(bv + 16 + g4*4);
        float4 bq0 = *(const float4*)(ppf + OFF_BQS + g4*4);
        float4 bq1 = *(const float4*)(ppf + OFF_BQS + 16 + g4*4);

        const int srcA = s + 32*(g4 & 1);
        const int srcB = srcA + 16;
        const bool selLo = (g4 < 2);

        const int njl = (wid == 3) ? 5 : 4;
        for (int jj = 0; jj < njl; jj++){
            const int j = (jj < 4) ? (wid + jj*4) : 16;
            f16x8 fup0 = u4h8(wsu4[OFF_FUP/4 + j*128 + wl]);
            f16x8 fup1 = u4h8(wsu4[OFF_FUP/4 + j*128 + 64 + wl]);
            float4 bu0 = *(const float4*)(bup + j*32 + g4*4);
            float4 bu1 = *(const float4*)(bup + j*32 + 16 + g4*4);
            float4 pp0 = *(const float4*)(ppf + OFF_PP + j*32 + g4*4);
            float4 pp1 = *(const float4*)(ppf + OFF_PP + j*32 + 16 + g4*4);
            uint4 tu0 = *(const uint4*)(ws32 + OFF_TUP + j*32 + g4*4);
            uint4 tu1 = *(const uint4*)(ws32 + OFF_TUP + j*32 + 16 + g4*4);

            f32x4 up0, up1;
            up0[0] = fdot2(xtp, tu0.x, bu0.x); up0[1] = fdot2(xtp, tu0.y, bu0.y);
            up0[2] = fdot2(xtp, tu0.z, bu0.z); up0[3] = fdot2(xtp, tu0.w, bu0.w);
            up1[0] = fdot2(xtp, tu1.x, bu1.x); up1[1] = fdot2(xtp, tu1.y, bu1.y);
            up1[2] = fdot2(xtp, tu1.z, bu1.z); up1[3] = fdot2(xtp, tu1.w, bu1.w);
            up0 = __builtin_amdgcn_mfma_f32_16x16x32_f16(fup0, ax, up0, 0,0,0);
            up1 = __builtin_amdgcn_mfma_f32_16x16x32_f16(fup1, ax, up1, 0,0,0);
            #pragma unroll
            for (int r=0;r<4;r++){ up0[r] = lrelu(up0[r]); up1[r] = lrelu(up1[r]); }

            const bool occ = !((bm>>j)&1u);
            const int rk = __popc((~bm) & ((1u<<j)-1u));
            if (occ){
                int rotq = (rk + s + (s>>2)) & 3;
                uint4 u;
                u.x = pkrtz(up0[0], up1[0]); u.y = pkrtz(up0[1], up1[1]);
                u.z = pkrtz(up0[2], up1[2]); u.w = pkrtz(up0[3], up1[3]);
                *(uint4*)&usl[s*QSTRIDE + rk*16 + ((g4 + rotq)&3)*4] = u;
            }
            f16x8 aup = repack(up0, up1, srcA, srcB, selLo);

            f32x4 uu0 = mk4(pp0), uu1 = mk4(pp1);
            uu0 = __builtin_amdgcn_mfma_f32_16x16x32_f16(fud0, aup, uu0, 0,0,0);
            uu1 = __builtin_amdgcn_mfma_f32_16x16x32_f16(fud1, aup, uu1, 0,0,0);
            #pragma unroll
            for (int r=0;r<4;r++){ uu0[r] = lrelu(uu0[r]); uu1[r] = lrelu(uu1[r]); }
            f16x8 auu = repack(uu0, uu1, srcA, srcB, selLo);

            f32x4 kk0 = mk4(bk0), kk1 = mk4(bk1);
            f32x4 vv0 = mk4(bv0), vv1 = mk4(bv1);
            f32x4 qq0 = mk4(bq0), qq1 = mk4(bq1);
            kk0 = __builtin_amdgcn_mfma_f32_16x16x32_f16(fk0, auu, kk0, 0,0,0);
            kk1 = __builtin_amdgcn_mfma_f32_16x16x32_f16(fk1, auu, kk1, 0,0,0);
            vv0 = __builtin_amdgcn_mfma_f32_16x16x32_f16(fv0, auu, vv0, 0,0,0);
            vv1 = __builtin_amdgcn_mfma_f32_16x16x32_f16(fv1, auu, vv1, 0,0,0);
            qq0 = __builtin_amdgcn_mfma_f32_16x16x32_f16(fq0, auu, qq0, 0,0,0);
            qq1 = __builtin_amdgcn_mfma_f32_16x16x32_f16(fq1, auu, qq1, 0,0,0);

            const int rot = (j + s + (s>>2)) & 3;
            const int grp = ((g4 + rot)&3)*4;
            uint4 kp, vp;
            kp.x = pkrtz(kk0[0], kk1[0]); kp.y = pkrtz(kk0[1], kk1[1]);
            kp.z = pkrtz(kk0[2], kk1[2]); kp.w = pkrtz(kk0[3], kk1[3]);
            vp.x = pkrtz(vv0[0], vv1[0]); vp.y = pkrtz(vv0[1], vv1[1]);
            vp.z = pkrtz(vv0[2], vv1[2]); vp.w = pkrtz(vv0[3], vv1[3]);
            *(uint4*)&ksl[s*KSTRIDE + j*16 + grp] = kp;
            *(uint4*)&vsl[s*KSTRIDE + j*16 + grp] = vp;
            if (occ){
                int rotq = (rk + s + (s>>2)) & 3;
                uint4 qp4;
                qp4.x = pkrtz(qq0[0], qq1[0]); qp4.y = pkrtz(qq0[1], qq1[1]);
                qp4.z = pkrtz(qq0[2], qq1[2]); qp4.w = pkrtz(qq0[3], qq1[3]);
                *(uint4*)&qsl[s*QSTRIDE + rk*16 + ((g4 + rotq)&3)*4] = qp4;
            }
        }
    }
    __syncthreads();

    // ---------------- phase 2: 128 pairs x 2 lanes, static indices only ------
    const int c  = tid & 1;           // half id; partner = tid^1 (same wave)
    const int pr = tid >> 1;          // pair id 0..127
    const int s2 = pr >> 3, q = pr & 7;
    if (sb + s2 >= B) return;

    // q row (both lanes full)
    unsigned qw[16];
    {
        int rot = (q + s2 + (s2>>2)) & 3;
        const unsigned* base = qsl + s2*QSTRIDE + q*16;
        #pragma unroll
        for (int a=0;a<4;a++){
            uint4 t = *(const uint4*)(base + ((a + rot)&3)*4);
            qw[4*a]=t.x; qw[4*a+1]=t.y; qw[4*a+2]=t.z; qw[4*a+3]=t.w;
        }
    }
    // scores: lane c computes 9 keys starting at c*8 (kj=8 overlap, harmless)
    float scl[9];
    #pragma unroll
    for (int i=0;i<9;i++){
        int kj = c*8 + i;
        unsigned kw[16];
        int rot = (kj + s2 + (s2>>2)) & 3;
        const unsigned* base = ksl + s2*KSTRIDE + kj*16;
        #pragma unroll
        for (int a=0;a<4;a++){
            uint4 t = *(const uint4*)(base + ((a + rot)&3)*4);
            kw[4*a]=t.x; kw[4*a+1]=t.y; kw[4*a+2]=t.z; kw[4*a+3]=t.w;
        }
        float s0=0.f,s1=0.f,s2a=0.f,s3=0.f;
        #pragma unroll
        for (int p=0;p<16;p+=4){
            s0  = fdot2(qw[p],   kw[p],   s0);
            s1  = fdot2(qw[p+1], kw[p+1], s1);
            s2a = fdot2(qw[p+2], kw[p+2], s2a);
            s3  = fdot2(qw[p+3], kw[p+3], s3);
        }
        scl[i] = (s0+s1)+(s2a+s3);
    }
    // exchange; rebuild full row with STATIC indices (value selects only)
    float rcv[9];
    #pragma unroll
    for (int i=0;i<9;i++) rcv[i] = __shfl_xor(scl[i], 1, 64);
    float sc[JN];
    #pragma unroll
    for (int i=0;i<8;i++) sc[i] = c ? rcv[i] : scl[i];
    sc[8] = c ? scl[0] : scl[8];
    #pragma unroll
    for (int i=1;i<9;i++) sc[8+i] = c ? scl[i] : rcv[i];

    float m = sc[0];
    #pragma unroll
    for (int kj=1;kj<JN;kj++) m = fmaxf(m, sc[kj]);
    float e[JN]; float sum = 0.f;
    #pragma unroll
    for (int kj=0;kj<JN;kj++){ e[kj] = __expf(sc[kj]-m); sum += e[kj]; }
    float ri = 1.0f/sum;

    // PV: lane c owns v dwords p = c*8..c*8+7 (LDS groups a = 2c, 2c+1)
    unsigned o[8];
    #pragma unroll
    for (int i=0;i<8;i++) o[i] = 0u;
    #pragma unroll
    for (int kj=0;kj<JN;kj++){
        float w = e[kj]*ri;
        unsigned w2 = pkrtz(w, w);
        int rot = (kj + s2 + (s2>>2)) & 3;
        const unsigned* base = vsl + s2*KSTRIDE + kj*16;
        uint4 t0 = *(const uint4*)(base + ((2*c   + rot)&3)*4);
        uint4 t1 = *(const uint4*)(base + ((2*c+1 + rot)&3)*4);
        unsigned vw[8] = {t0.x,t0.y,t0.z,t0.w,t1.x,t1.y,t1.z,t1.w};
        #pragma unroll
        for (int i=0;i<8;i++) o[i] = pkfma(w2, vw[i], o[i]);
    }

    // exchange o (8 dwords), rebuild oAll with static selects; each lane then
    // computes its OWN 16-channel half of d1 (t) fully.
    unsigned rcvO[8];
    #pragma unroll
    for (int i=0;i<8;i++) rcvO[i] = (unsigned)__shfl_xor((int)o[i], 1, 64);
    unsigned oAll[16];
    #pragma unroll
    for (int i=0;i<8;i++){ oAll[i] = c ? rcvO[i] : o[i]; oAll[8+i] = c ? o[i] : rcvO[i]; }

    const unsigned* wd1I = ws32 + OFF_WD1I;
    const unsigned* wd2  = ws32 + OFF_WD2;
    float tw[16];
    #pragma unroll
    for (int i=0;i<16;i++) tw[i] = bd1[c*16 + i];           // runtime addr, fine
    #pragma unroll
    for (int p=0;p<16;p++){
        unsigned a = oAll[p];
        const unsigned* wrow = wd1I + p*32 + c*16;          // runtime addr, fine
        #pragma unroll
        for (int i=0;i<16;i++) tw[i] = fdot2(a, wrow[i], tw[i]);
    }
    unsigned tpo[8];                                         // = tp[c*8 + i]
    #pragma unroll
    for (int i=0;i<8;i++) tpo[i] = pkrtz(lrelu(tw[2*i]), lrelu(tw[2*i+1]));

    // d2: z full 32 channels, accumulated from own 8 tp dwords; residual init
    // on own half via STATIC writes + value selects.
    float z[32];
    #pragma unroll
    for (int h=0;h<32;h++) z[h] = 0.f;
    {
        int rot = (q + s2 + (s2>>2)) & 3;
        const unsigned* base = usl + s2*QSTRIDE + q*16;
        #pragma unroll
        for (int aa=0; aa<2; aa++){
            uint4 tt = *(const uint4*)(base + (((2*c+aa) + rot)&3)*4);
            unsigned pw[4] = {tt.x, tt.y, tt.z, tt.w};
            #pragma unroll
            for (int i=0;i<4;i++){
                int pb = 4*aa + i;                           // 0..7 static
                h2v r = u2h(pw[i]);
                float vlo = (float)r.x + bd2[c*8 + pb];      // runtime addr, fine
                float vhi = (float)r.y + bd2[16 + c*8 + pb];
                z[pb]      = c ? 0.f : vlo;
                z[8 + pb]  = c ? vlo : 0.f;
                z[16 + pb] = c ? 0.f : vhi;
                z[24 + pb] = c ? vhi : 0.f;
            }
        }
    }
    #pragma unroll
    for (int i=0;i<8;i++){
        unsigned a = tpo[i];
        const unsigned* wrow = wd2 + (c*8 + i)*32;           // runtime addr, fine
        #pragma unroll
        for (int h=0;h<32;h++) z[h] = fdot2(a, wrow[h], z[h]);
    }

    // y = (z_self + z_partner) . Ws : dot partials fully, combine scalar
    float y0=0.f, y1=0.f;
    #pragma unroll
    for (int h=0;h<32;h+=2){ y0 = fmaf(z[h], Ws[h], y0); y1 = fmaf(z[h+1], Ws[h+1], y1); }
    float yp = y0 + y1;
    yp += __shfl_xor(yp, 1, 64);
    if (c == 0){
        float y = yp + bs[0];
        out[((size_t)(sb + s2))*8 + q] = 1.0f/(1.0f + __expf(-y));
    }
}

extern "C" void kernel_launch(void* const* d_in, const int* in_sizes, int n_in,
                              void* d_out, int out_size, void* d_ws, size_t ws_size,
                              hipStream_t stream) {
    (void)n_in; (void)out_size; (void)ws_size;
    const float* x   = (const float*)d_in[0];
    const void*  m   = d_in[1];
    const float* pos = (const float*)d_in[2];
    const float* Wup = (const float*)d_in[3];  const float* bup = (const float*)d_in[4];
    const float* Wud = (const float*)d_in[5];  const float* bud = (const float*)d_in[6];
    const float* Wq  = (const float*)d_in[7];  const float* bq  = (const float*)d_in[8];
    const float* Wk  = (const float*)d_in[9];  const float* bk  = (const float*)d_in[10];
    const float* Wv  = (const float*)d_in[11]; const float* bv  = (const float*)d_in[12];
    const float* Wd1 = (const float*)d_in[13]; const float* bd1 = (const float*)d_in[14];
    const float* Wd2 = (const float*)d_in[15]; const float* bd2 = (const float*)d_in[16];
    const float* Ws  = (const float*)d_in[17]; const float* bs  = (const float*)d_in[18];
    float* out = (float*)d_out;
    int B = in_sizes[0] / (JN*2);

    unsigned char* wsb = (unsigned char*)d_ws;
    unsigned* ws32  = (unsigned*)wsb;
    unsigned* bmask = (unsigned*)(wsb + HDR_BYTES);

    prep_kernel<<<(B+255)/256, 256, 0, stream>>>(m, pos, Wup, Wud, bud, Wq, bq,
                                                 Wk, Wv, Wd1, Wd2, ws32, bmask, B);
    fused_kernel<<<(B+15)/16, 256, 0, stream>>>(x, bmask, ws32, bup, bk, bv,
                                                bd1, bd2, Ws, bs, out, B);
}

// Round 13
// 69.304 us; speedup vs baseline: 3.6688x; 1.9924x over previous
//
#include <hip/hip_runtime.h>
#include <hip/hip_fp16.h>

#define JN 17

typedef __fp16 h2v __attribute__((ext_vector_type(2)));
typedef _Float16 f16x8 __attribute__((ext_vector_type(8)));
typedef float f32x4 __attribute__((ext_vector_type(4)));

__device__ __forceinline__ float lrelu(float x){ return fmaxf(x, 0.01f*x); }
__device__ __forceinline__ unsigned h2u(h2v h){ unsigned u; __builtin_memcpy(&u, &h, 4); return u; }
__device__ __forceinline__ h2v u2h(unsigned u){ h2v h; __builtin_memcpy(&h, &u, 4); return h; }
__device__ __forceinline__ unsigned pkrtz(float a, float b){ return h2u(__builtin_amdgcn_cvt_pkrtz(a,b)); }
__device__ __forceinline__ float fdot2(unsigned a, unsigned b, float c){
    return __builtin_amdgcn_fdot2(u2h(a), u2h(b), c, false);
}
__device__ __forceinline__ unsigned pkfma(unsigned a, unsigned b, unsigned c){
    h2v r = u2h(a)*u2h(b) + u2h(c);
    return h2u(r);
}
__device__ __forceinline__ f16x8 u4h8(uint4 u){ union{uint4 u; f16x8 h;} c; c.u=u; return c.h; }
__device__ __forceinline__ f32x4 mk4(float4 v){ f32x4 r; r[0]=v.x; r[1]=v.y; r[2]=v.z; r[3]=v.w; return r; }

// C(t0,t1) -> B-frag of next MFMA via cross-lane permute (values post-activation).
__device__ __forceinline__ f16x8 repack(f32x4 c0, f32x4 c1, int srcA, int srcB, bool selLo){
    unsigned pkA = pkrtz(c0[0], c0[1]);
    unsigned pkB = pkrtz(c0[2], c0[3]);
    unsigned pkC = pkrtz(c1[0], c1[1]);
    unsigned pkD = pkrtz(c1[2], c1[3]);
    unsigned rA0 = (unsigned)__shfl((int)pkA, srcA, 64);
    unsigned rB0 = (unsigned)__shfl((int)pkB, srcA, 64);
    unsigned rC0 = (unsigned)__shfl((int)pkC, srcA, 64);
    unsigned rD0 = (unsigned)__shfl((int)pkD, srcA, 64);
    unsigned rA1 = (unsigned)__shfl((int)pkA, srcB, 64);
    unsigned rB1 = (unsigned)__shfl((int)pkB, srcB, 64);
    unsigned rC1 = (unsigned)__shfl((int)pkC, srcB, 64);
    unsigned rD1 = (unsigned)__shfl((int)pkD, srcB, 64);
    uint4 u;
    u.x = selLo ? rA0 : rC0;
    u.y = selLo ? rB0 : rD0;
    u.z = selLo ? rA1 : rC1;
    u.w = selLo ? rB1 : rD1;
    return u4h8(u);
}

// ws header layout (u32 units), first 65536 bytes
#define OFF_PP    0
#define OFF_BQS   544
#define OFF_FQ    576
#define OFF_FD1   1088     // Wd1 A-frag, rows permuted to o's (h,h+16) dword order
#define OFF_FD2   1600     // Wd2 A-frag, standard row order
#define OFF_FUD   2112
#define OFF_FK    2624
#define OFF_FV    3136
#define OFF_TUP   3648
#define OFF_FUP   4192
#define HDR_BYTES 65536

#define KSTRIDE 276
#define QSTRIDE 132

// ---------------- prep ------------------------------------------------------
__global__ __launch_bounds__(256,1)
void prep_kernel(const void* __restrict__ mraw, const float* __restrict__ pos,
                 const float* __restrict__ Wup,
                 const float* __restrict__ Wud, const float* __restrict__ bud,
                 const float* __restrict__ Wq,  const float* __restrict__ bq,
                 const float* __restrict__ Wk,  const float* __restrict__ Wv,
                 const float* __restrict__ Wd1, const float* __restrict__ Wd2,
                 unsigned* __restrict__ ws32, unsigned* __restrict__ bmask, int B)
{
    int g = blockIdx.x*256 + threadIdx.x;
    const float isq = 0.17677669529663687f;

    const unsigned* mw = (const unsigned*)mraw;
    bool f3f=false, nz=false;
    #pragma unroll
    for (int i=0;i<17;i++){
        unsigned w = mw[i];
        if ((w>>24) == 0x3Fu) f3f = true;
        if (w & 0xFFFFFF00u)  nz  = true;
    }
    int mode = f3f ? 2 : (nz ? 1 : 0);
    if (g < B){
        unsigned bm = 0; size_t base = (size_t)g*JN;
        if (mode == 0){
            const int* mi = (const int*)mraw;
            #pragma unroll
            for (int j=0;j<JN;j++) if (mi[base+j] != 0) bm |= (1u<<j);
        } else if (mode == 1){
            const unsigned char* mb = (const unsigned char*)mraw;
            #pragma unroll
            for (int j=0;j<JN;j++) if (mb[base+j] != 0) bm |= (1u<<j);
        } else {
            const float* mf = (const float*)mraw;
            #pragma unroll
            for (int j=0;j<JN;j++) if (mf[base+j] != 0.f) bm |= (1u<<j);
        }
        bmask[g] = bm;
    }
    if (g < 544){
        int j = g >> 5, h = g & 31;
        float acc = bud[h];
        #pragma unroll
        for (int c=0;c<32;c++) acc = fmaf(pos[j*32+c], Wud[(32+c)*32 + h], acc);
        ((float*)ws32)[OFF_PP + g] = acc;
        int t = (g >> 4) & 1, c = g & 15;
        int col = j*32 + t*16 + c;
        ws32[OFF_TUP + g] = pkrtz(Wup[32*544 + col], Wup[33*544 + col]);
    }
    if (g < 32) ((float*)ws32)[OFF_BQS + g] = bq[g]*isq;
    if (g < 512){
        int t = g >> 8, rmn = g & 255, lane = rmn >> 2, i2 = rmn & 3;
        int k0 = (lane>>4)*8 + 2*i2, c = (lane&15) + 16*t;
        ws32[OFF_FUD + g] = pkrtz(Wud[k0*32 + c],     Wud[(k0+1)*32 + c]);
        ws32[OFF_FK  + g] = pkrtz(Wk [k0*32 + c],     Wk [(k0+1)*32 + c]);
        ws32[OFF_FV  + g] = pkrtz(Wv [k0*32 + c],     Wv [(k0+1)*32 + c]);
        ws32[OFF_FQ  + g] = pkrtz(Wq [k0*32 + c]*isq, Wq [(k0+1)*32 + c]*isq);
        // fd1: input rows follow o's dword order: element 2p -> ch p, 2p+1 -> ch p+16
        ws32[OFF_FD1 + g] = pkrtz(Wd1[(k0>>1)*32 + c], Wd1[(16 + (k0>>1))*32 + c]);
        ws32[OFF_FD2 + g] = pkrtz(Wd2[k0*32 + c],     Wd2[(k0+1)*32 + c]);
    }
    if (g < 8704){
        int j = g >> 9, r = g & 511, t = r >> 8, rr = r & 255, lane = rr >> 2, i2 = rr & 3;
        int k0 = (lane>>4)*8 + 2*i2;
        int col = j*32 + (lane&15) + 16*t;
        ws32[OFF_FUP + g] = pkrtz(Wup[k0*544 + col], Wup[(k0+1)*544 + col]);
    }
}

// ---------------- fused kernel: 16 samples / block (4 waves) -----------------
// Phase1 (transposed MFMA) -> LDS. Phase2a (128 lanes): scores+softmax+PV -> o.
// Phase2b (all 256 lanes): d1/d2 batched as MFMAs over 128 rows.
__global__ __launch_bounds__(256,3)
void fused_kernel(const float* __restrict__ x, const unsigned* __restrict__ bmask,
                  const unsigned* __restrict__ ws32,
                  const float* __restrict__ bup, const float* __restrict__ bk,
                  const float* __restrict__ bv,  const float* __restrict__ bd1,
                  const float* __restrict__ bd2, const float* __restrict__ Ws,
                  const float* __restrict__ bs,  float* __restrict__ out, int B)
{
    __shared__ unsigned ksl[16*KSTRIDE];
    __shared__ unsigned vsl[16*KSTRIDE];
    __shared__ unsigned qsl[16*QSTRIDE];
    __shared__ unsigned usl[16*QSTRIDE];

    const int tid = threadIdx.x;
    const int wid = tid >> 6, wl = tid & 63;
    const int sb  = blockIdx.x * 16;
    const int s   = wl & 15, g4 = wl >> 4;
    const int smax = B - 1;

    // ---------------- phase 1 (round-10, verified) ----------------
    {
        int sA = sb + s; if (sA > smax) sA = smax;
        f16x8 ax;
        {
            const float* xr = x + (size_t)sA*34 + g4*8;
            float2 a0 = *(const float2*)(xr);
            float2 a1 = *(const float2*)(xr+2);
            float2 a2 = *(const float2*)(xr+4);
            float2 a3 = *(const float2*)(xr+6);
            uint4 u; u.x=pkrtz(a0.x,a0.y); u.y=pkrtz(a1.x,a1.y);
            u.z=pkrtz(a2.x,a2.y); u.w=pkrtz(a3.x,a3.y);
            ax = u4h8(u);
        }
        const unsigned bm = bmask[sA];
        float2 xt2 = *(const float2*)(x + (size_t)sA*34 + 32);
        const unsigned xtp = pkrtz(xt2.x, xt2.y);

        const uint4* wsu4 = (const uint4*)ws32;
        f16x8 fud0 = u4h8(wsu4[OFF_FUD/4 + wl]);
        f16x8 fud1 = u4h8(wsu4[OFF_FUD/4 + 64 + wl]);
        f16x8 fk0  = u4h8(wsu4[OFF_FK/4  + wl]);
        f16x8 fk1  = u4h8(wsu4[OFF_FK/4  + 64 + wl]);
        f16x8 fv0  = u4h8(wsu4[OFF_FV/4  + wl]);
        f16x8 fv1  = u4h8(wsu4[OFF_FV/4  + 64 + wl]);
        f16x8 fq0  = u4h8(wsu4[OFF_FQ/4  + wl]);
        f16x8 fq1  = u4h8(wsu4[OFF_FQ/4  + 64 + wl]);

        const float* ppf = (const float*)ws32;
        float4 bk0 = *(const float4*)(bk + g4*4);
        float4 bk1 = *(const float4*)(bk + 16 + g4*4);
        float4 bv0 = *(const float4*)(bv + g4*4);
        float4 bv1 = *(const float4*)(bv + 16 + g4*4);
        float4 bq0 = *(const float4*)(ppf + OFF_BQS + g4*4);
        float4 bq1 = *(const float4*)(ppf + OFF_BQS + 16 + g4*4);

        const int srcA = s + 32*(g4 & 1);
        const int srcB = srcA + 16;
        const bool selLo = (g4 < 2);

        const int njl = (wid == 3) ? 5 : 4;
        for (int jj = 0; jj < njl; jj++){
            const int j = (jj < 4) ? (wid + jj*4) : 16;
            f16x8 fup0 = u4h8(wsu4[OFF_FUP/4 + j*128 + wl]);
            f16x8 fup1 = u4h8(wsu4[OFF_FUP/4 + j*128 + 64 + wl]);
            float4 bu0 = *(const float4*)(bup + j*32 + g4*4);
            float4 bu1 = *(const float4*)(bup + j*32 + 16 + g4*4);
            float4 pp0 = *(const float4*)(ppf + OFF_PP + j*32 + g4*4);
            float4 pp1 = *(const float4*)(ppf + OFF_PP + j*32 + 16 + g4*4);
            uint4 tu0 = *(const uint4*)(ws32 + OFF_TUP + j*32 + g4*4);
            uint4 tu1 = *(const uint4*)(ws32 + OFF_TUP + j*32 + 16 + g4*4);

            f32x4 up0, up1;
            up0[0] = fdot2(xtp, tu0.x, bu0.x); up0[1] = fdot2(xtp, tu0.y, bu0.y);
            up0[2] = fdot2(xtp, tu0.z, bu0.z); up0[3] = fdot2(xtp, tu0.w, bu0.w);
            up1[0] = fdot2(xtp, tu1.x, bu1.x); up1[1] = fdot2(xtp, tu1.y, bu1.y);
            up1[2] = fdot2(xtp, tu1.z, bu1.z); up1[3] = fdot2(xtp, tu1.w, bu1.w);
            up0 = __builtin_amdgcn_mfma_f32_16x16x32_f16(fup0, ax, up0, 0,0,0);
            up1 = __builtin_amdgcn_mfma_f32_16x16x32_f16(fup1, ax, up1, 0,0,0);
            #pragma unroll
            for (int r=0;r<4;r++){ up0[r] = lrelu(up0[r]); up1[r] = lrelu(up1[r]); }

            const bool occ = !((bm>>j)&1u);
            const int rk = __popc((~bm) & ((1u<<j)-1u));
            if (occ){
                int rotq = (rk + s + (s>>2)) & 3;
                uint4 u;
                u.x = pkrtz(up0[0], up1[0]); u.y = pkrtz(up0[1], up1[1]);
                u.z = pkrtz(up0[2], up1[2]); u.w = pkrtz(up0[3], up1[3]);
                *(uint4*)&usl[s*QSTRIDE + rk*16 + ((g4 + rotq)&3)*4] = u;
            }
            f16x8 aup = repack(up0, up1, srcA, srcB, selLo);

            f32x4 uu0 = mk4(pp0), uu1 = mk4(pp1);
            uu0 = __builtin_amdgcn_mfma_f32_16x16x32_f16(fud0, aup, uu0, 0,0,0);
            uu1 = __builtin_amdgcn_mfma_f32_16x16x32_f16(fud1, aup, uu1, 0,0,0);
            #pragma unroll
            for (int r=0;r<4;r++){ uu0[r] = lrelu(uu0[r]); uu1[r] = lrelu(uu1[r]); }
            f16x8 auu = repack(uu0, uu1, srcA, srcB, selLo);

            f32x4 kk0 = mk4(bk0), kk1 = mk4(bk1);
            f32x4 vv0 = mk4(bv0), vv1 = mk4(bv1);
            f32x4 qq0 = mk4(bq0), qq1 = mk4(bq1);
            kk0 = __builtin_amdgcn_mfma_f32_16x16x32_f16(fk0, auu, kk0, 0,0,0);
            kk1 = __builtin_amdgcn_mfma_f32_16x16x32_f16(fk1, auu, kk1, 0,0,0);
            vv0 = __builtin_amdgcn_mfma_f32_16x16x32_f16(fv0, auu, vv0, 0,0,0);
            vv1 = __builtin_amdgcn_mfma_f32_16x16x32_f16(fv1, auu, vv1, 0,0,0);
            qq0 = __builtin_amdgcn_mfma_f32_16x16x32_f16(fq0, auu, qq0, 0,0,0);
            qq1 = __builtin_amdgcn_mfma_f32_16x16x32_f16(fq1, auu, qq1, 0,0,0);

            const int rot = (j + s + (s>>2)) & 3;
            const int grp = ((g4 + rot)&3)*4;
            uint4 kp, vp;
            kp.x = pkrtz(kk0[0], kk1[0]); kp.y = pkrtz(kk0[1], kk1[1]);
            kp.z = pkrtz(kk0[2], kk1[2]); kp.w = pkrtz(kk0[3], kk1[3]);
            vp.x = pkrtz(vv0[0], vv1[0]); vp.y = pkrtz(vv0[1], vv1[1]);
            vp.z = pkrtz(vv0[2], vv1[2]); vp.w = pkrtz(vv0[3], vv1[3]);
            *(uint4*)&ksl[s*KSTRIDE + j*16 + grp] = kp;
            *(uint4*)&vsl[s*KSTRIDE + j*16 + grp] = vp;
            if (occ){
                int rotq = (rk + s + (s>>2)) & 3;
                uint4 qp4;
                qp4.x = pkrtz(qq0[0], qq1[0]); qp4.y = pkrtz(qq0[1], qq1[1]);
                qp4.z = pkrtz(qq0[2], qq1[2]); qp4.w = pkrtz(qq0[3], qq1[3]);
                *(uint4*)&qsl[s*QSTRIDE + rk*16 + ((g4 + rotq)&3)*4] = qp4;
            }
        }
    }
    __syncthreads();

    // ---------------- phase 2a: 128 lanes (s,q): scores + softmax + PV -------
    const int pr = tid;
    const int s2 = (pr >> 3) & 15, q = pr & 7;
    const bool act2 = (tid < 128) && (sb + s2 < B);
    unsigned o[16];
    #pragma unroll
    for (int p=0;p<16;p++) o[p] = 0u;
    if (act2){
        unsigned qw[16];
        {
            int rot = (q + s2 + (s2>>2)) & 3;
            const unsigned* base = qsl + s2*QSTRIDE + q*16;
            #pragma unroll
            for (int a=0;a<4;a++){
                uint4 t = *(const uint4*)(base + ((a + rot)&3)*4);
                qw[4*a]=t.x; qw[4*a+1]=t.y; qw[4*a+2]=t.z; qw[4*a+3]=t.w;
            }
        }
        float sc[JN];
        #pragma unroll
        for (int kj=0; kj<JN; kj++){
            unsigned kw[16];
            int rot = (kj + s2 + (s2>>2)) & 3;
            const unsigned* base = ksl + s2*KSTRIDE + kj*16;
            #pragma unroll
            for (int a=0;a<4;a++){
                uint4 t = *(const uint4*)(base + ((a + rot)&3)*4);
                kw[4*a]=t.x; kw[4*a+1]=t.y; kw[4*a+2]=t.z; kw[4*a+3]=t.w;
            }
            float s0=0.f,s1=0.f,s2a=0.f,s3=0.f;
            #pragma unroll
            for (int p=0;p<16;p+=4){
                s0  = fdot2(qw[p],   kw[p],   s0);
                s1  = fdot2(qw[p+1], kw[p+1], s1);
                s2a = fdot2(qw[p+2], kw[p+2], s2a);
                s3  = fdot2(qw[p+3], kw[p+3], s3);
            }
            sc[kj] = (s0+s1)+(s2a+s3);
        }
        float m = sc[0];
        #pragma unroll
        for (int kj=1;kj<JN;kj++) m = fmaxf(m, sc[kj]);
        float e[JN]; float sum = 0.f;
        #pragma unroll
        for (int kj=0;kj<JN;kj++){ e[kj] = __expf(sc[kj]-m); sum += e[kj]; }
        float ri = 1.0f/sum;
        #pragma unroll
        for (int kj=0;kj<JN;kj++){
            float w = e[kj]*ri;
            unsigned w2 = pkrtz(w, w);
            unsigned vw[16];
            int rot = (kj + s2 + (s2>>2)) & 3;
            const unsigned* base = vsl + s2*KSTRIDE + kj*16;
            #pragma unroll
            for (int a=0;a<4;a++){
                uint4 t = *(const uint4*)(base + ((a + rot)&3)*4);
                vw[4*a]=t.x; vw[4*a+1]=t.y; vw[4*a+2]=t.z; vw[4*a+3]=t.w;
            }
            #pragma unroll
            for (int p=0;p<16;p++) o[p] = pkfma(w2, vw[p], o[p]);
        }
    }
    __syncthreads();          // all k/v reads done; ksl becomes dead storage
    if (act2){
        int rot = (pr>>1)&3;
        *(uint4*)&ksl[pr*16 + ((0+rot)&3)*4] = make_uint4(o[0],o[1],o[2],o[3]);
        *(uint4*)&ksl[pr*16 + ((1+rot)&3)*4] = make_uint4(o[4],o[5],o[6],o[7]);
        *(uint4*)&ksl[pr*16 + ((2+rot)&3)*4] = make_uint4(o[8],o[9],o[10],o[11]);
        *(uint4*)&ksl[pr*16 + ((3+rot)&3)*4] = make_uint4(o[12],o[13],o[14],o[15]);
    }
    __syncthreads();

    // ---------------- phase 2b: all 4 waves, d1/d2 as batched MFMAs ----------
    {
        const int rid = wl & 15, g4b = wl >> 4;
        const uint4* wsu4 = (const uint4*)ws32;
        f16x8 fd1_0 = u4h8(wsu4[OFF_FD1/4 + wl]);
        f16x8 fd1_1 = u4h8(wsu4[OFF_FD1/4 + 64 + wl]);
        f16x8 fd2_0 = u4h8(wsu4[OFF_FD2/4 + wl]);
        f16x8 fd2_1 = u4h8(wsu4[OFF_FD2/4 + 64 + wl]);
        float4 bd10 = *(const float4*)(bd1 + g4b*4);
        float4 bd11 = *(const float4*)(bd1 + 16 + g4b*4);
        float4 bd20 = *(const float4*)(bd2 + g4b*4);
        float4 bd21 = *(const float4*)(bd2 + 16 + g4b*4);
        float4 ws0  = *(const float4*)(Ws + g4b*4);
        float4 ws1  = *(const float4*)(Ws + 16 + g4b*4);
        const float bsv = bs[0];
        const int srcA = rid + 32*(g4b & 1);
        const int srcB = srcA + 16;
        const bool selLo = (g4b < 2);

        #pragma unroll
        for (int gg=0; gg<2; gg++){
            const int rowg = (wid*2 + gg)*16 + rid;       // 0..127
            // B-frag of o^T (channel order = o dword order; fd1 matches)
            int roto = (rowg>>1)&3;
            f16x8 bo = u4h8(*(const uint4*)&ksl[rowg*16 + ((g4b + roto)&3)*4]);

            f32x4 t0 = mk4(bd10), t1 = mk4(bd11);
            t0 = __builtin_amdgcn_mfma_f32_16x16x32_f16(fd1_0, bo, t0, 0,0,0);
            t1 = __builtin_amdgcn_mfma_f32_16x16x32_f16(fd1_1, bo, t1, 0,0,0);
            #pragma unroll
            for (int r=0;r<4;r++){ t0[r] = lrelu(t0[r]); t1[r] = lrelu(t1[r]); }
            f16x8 bt = repack(t0, t1, srcA, srcB, selLo);

            // d2 C-init: residual (usl) + bd2
            const int s2b = rowg >> 3, qb = rowg & 7;
            int rotq = (qb + s2b + (s2b>>2)) & 3;
            uint4 ur = *(const uint4*)&usl[s2b*QSTRIDE + qb*16 + ((g4b + rotq)&3)*4];
            unsigned urr[4] = {ur.x, ur.y, ur.z, ur.w};
            f32x4 z0, z1;
            {
                h2v r0 = u2h(urr[0]), r1 = u2h(urr[1]), r2 = u2h(urr[2]), r3 = u2h(urr[3]);
                z0[0] = (float)r0.x + bd20.x; z1[0] = (float)r0.y + bd21.x;
                z0[1] = (float)r1.x + bd20.y; z1[1] = (float)r1.y + bd21.y;
                z0[2] = (float)r2.x + bd20.z; z1[2] = (float)r2.y + bd21.z;
                z0[3] = (float)r3.x + bd20.w; z1[3] = (float)r3.y + bd21.w;
            }
            z0 = __builtin_amdgcn_mfma_f32_16x16x32_f16(fd2_0, bt, z0, 0,0,0);
            z1 = __builtin_amdgcn_mfma_f32_16x16x32_f16(fd2_1, bt, z1, 0,0,0);

            float yp = z0[0]*ws0.x + z0[1]*ws0.y + z0[2]*ws0.z + z0[3]*ws0.w
                     + z1[0]*ws1.x + z1[1]*ws1.y + z1[2]*ws1.z + z1[3]*ws1.w;
            yp += __shfl_xor(yp, 16, 64);
            yp += __shfl_xor(yp, 32, 64);
            if (g4b == 0 && sb + s2b < B){
                float y = yp + bsv;
                out[((size_t)(sb + s2b))*8 + qb] = 1.0f/(1.0f + __expf(-y));
            }
        }
    }
}

extern "C" void kernel_launch(void* const* d_in, const int* in_sizes, int n_in,
                              void* d_out, int out_size, void* d_ws, size_t ws_size,
                              hipStream_t stream) {
    (void)n_in; (void)out_size; (void)ws_size;
    const float* x   = (const float*)d_in[0];
    const void*  m   = d_in[1];
    const float* pos = (const float*)d_in[2];
    const float* Wup = (const float*)d_in[3];  const float* bup = (const float*)d_in[4];
    const float* Wud = (const float*)d_in[5];  const float* bud = (const float*)d_in[6];
    const float* Wq  = (const float*)d_in[7];  const float* bq  = (const float*)d_in[8];
    const float* Wk  = (const float*)d_in[9];  const float* bk  = (const float*)d_in[10];
    const float* Wv  = (const float*)d_in[11]; const float* bv  = (const float*)d_in[12];
    const float* Wd1 = (const float*)d_in[13]; const float* bd1 = (const float*)d_in[14];
    const float* Wd2 = (const float*)d_in[15]; const float* bd2 = (const float*)d_in[16];
    const float* Ws  = (const float*)d_in[17]; const float* bs  = (const float*)d_in[18];
    float* out = (float*)d_out;
    int B = in_sizes[0] / (JN*2);

    unsigned char* wsb = (unsigned char*)d_ws;
    unsigned* ws32  = (unsigned*)wsb;
    unsigned* bmask = (unsigned*)(wsb + HDR_BYTES);

    prep_kernel<<<(B+255)/256, 256, 0, stream>>>(m, pos, Wup, Wud, bud, Wq, bq,
                                                 Wk, Wv, Wd1, Wd2, ws32, bmask, B);
    fused_kernel<<<(B+15)/16, 256, 0, stream>>>(x, bmask, ws32, bup, bk, bv,
                                                bd1, bd2, Ws, bs, out, B);
}

// Round 14
// 65.883 us; speedup vs baseline: 3.8593x; 1.0519x over previous
//
#include <hip/hip_runtime.h>
#include <hip/hip_fp16.h>

#define JN 17

typedef __fp16 h2v __attribute__((ext_vector_type(2)));
typedef _Float16 f16x8 __attribute__((ext_vector_type(8)));
typedef float f32x4 __attribute__((ext_vector_type(4)));

__device__ __forceinline__ float lrelu(float x){ return fmaxf(x, 0.01f*x); }
__device__ __forceinline__ unsigned h2u(h2v h){ unsigned u; __builtin_memcpy(&u, &h, 4); return u; }
__device__ __forceinline__ h2v u2h(unsigned u){ h2v h; __builtin_memcpy(&h, &u, 4); return h; }
__device__ __forceinline__ unsigned pkrtz(float a, float b){ return h2u(__builtin_amdgcn_cvt_pkrtz(a,b)); }
__device__ __forceinline__ float fdot2(unsigned a, unsigned b, float c){
    return __builtin_amdgcn_fdot2(u2h(a), u2h(b), c, false);
}
__device__ __forceinline__ unsigned pkfma(unsigned a, unsigned b, unsigned c){
    h2v r = u2h(a)*u2h(b) + u2h(c);
    return h2u(r);
}
__device__ __forceinline__ f16x8 u4h8(uint4 u){ union{uint4 u; f16x8 h;} c; c.u=u; return c.h; }
__device__ __forceinline__ f32x4 mk4(float4 v){ f32x4 r; r[0]=v.x; r[1]=v.y; r[2]=v.z; r[3]=v.w; return r; }

// C(t0,t1) -> B-frag of next MFMA via cross-lane permute (values post-activation).
__device__ __forceinline__ f16x8 repack(f32x4 c0, f32x4 c1, int srcA, int srcB, bool selLo){
    unsigned pkA = pkrtz(c0[0], c0[1]);
    unsigned pkB = pkrtz(c0[2], c0[3]);
    unsigned pkC = pkrtz(c1[0], c1[1]);
    unsigned pkD = pkrtz(c1[2], c1[3]);
    unsigned rA0 = (unsigned)__shfl((int)pkA, srcA, 64);
    unsigned rB0 = (unsigned)__shfl((int)pkB, srcA, 64);
    unsigned rC0 = (unsigned)__shfl((int)pkC, srcA, 64);
    unsigned rD0 = (unsigned)__shfl((int)pkD, srcA, 64);
    unsigned rA1 = (unsigned)__shfl((int)pkA, srcB, 64);
    unsigned rB1 = (unsigned)__shfl((int)pkB, srcB, 64);
    unsigned rC1 = (unsigned)__shfl((int)pkC, srcB, 64);
    unsigned rD1 = (unsigned)__shfl((int)pkD, srcB, 64);
    uint4 u;
    u.x = selLo ? rA0 : rC0;
    u.y = selLo ? rB0 : rD0;
    u.z = selLo ? rA1 : rC1;
    u.w = selLo ? rB1 : rD1;
    return u4h8(u);
}

// ws header layout (u32 units), first 65536 bytes
#define OFF_PP    0
#define OFF_BQS   544
#define OFF_FQ    576
#define OFF_FD1   1088     // Wd1 A-frag, rows permuted to o's (h,h+16) dword order
#define OFF_FD2   1600     // Wd2 A-frag, standard row order
#define OFF_FUD   2112
#define OFF_FK    2624
#define OFF_FV    3136
#define OFF_TUP   3648
#define OFF_FUP   4192
#define HDR_BYTES 65536

#define KSTRIDE 276
#define QSTRIDE 132

// ---------------- prep ------------------------------------------------------
__global__ __launch_bounds__(256,1)
void prep_kernel(const void* __restrict__ mraw, const float* __restrict__ pos,
                 const float* __restrict__ Wup,
                 const float* __restrict__ Wud, const float* __restrict__ bud,
                 const float* __restrict__ Wq,  const float* __restrict__ bq,
                 const float* __restrict__ Wk,  const float* __restrict__ Wv,
                 const float* __restrict__ Wd1, const float* __restrict__ Wd2,
                 unsigned* __restrict__ ws32, unsigned* __restrict__ bmask, int B)
{
    int g = blockIdx.x*256 + threadIdx.x;
    const float isq = 0.17677669529663687f;

    const unsigned* mw = (const unsigned*)mraw;
    bool f3f=false, nz=false;
    #pragma unroll
    for (int i=0;i<17;i++){
        unsigned w = mw[i];
        if ((w>>24) == 0x3Fu) f3f = true;
        if (w & 0xFFFFFF00u)  nz  = true;
    }
    int mode = f3f ? 2 : (nz ? 1 : 0);
    if (g < B){
        unsigned bm = 0; size_t base = (size_t)g*JN;
        if (mode == 0){
            const int* mi = (const int*)mraw;
            #pragma unroll
            for (int j=0;j<JN;j++) if (mi[base+j] != 0) bm |= (1u<<j);
        } else if (mode == 1){
            const unsigned char* mb = (const unsigned char*)mraw;
            #pragma unroll
            for (int j=0;j<JN;j++) if (mb[base+j] != 0) bm |= (1u<<j);
        } else {
            const float* mf = (const float*)mraw;
            #pragma unroll
            for (int j=0;j<JN;j++) if (mf[base+j] != 0.f) bm |= (1u<<j);
        }
        bmask[g] = bm;
    }
    if (g < 544){
        int j = g >> 5, h = g & 31;
        float acc = bud[h];
        #pragma unroll
        for (int c=0;c<32;c++) acc = fmaf(pos[j*32+c], Wud[(32+c)*32 + h], acc);
        ((float*)ws32)[OFF_PP + g] = acc;
        int t = (g >> 4) & 1, c = g & 15;
        int col = j*32 + t*16 + c;
        ws32[OFF_TUP + g] = pkrtz(Wup[32*544 + col], Wup[33*544 + col]);
    }
    if (g < 32) ((float*)ws32)[OFF_BQS + g] = bq[g]*isq;
    if (g < 512){
        int t = g >> 8, rmn = g & 255, lane = rmn >> 2, i2 = rmn & 3;
        int k0 = (lane>>4)*8 + 2*i2, c = (lane&15) + 16*t;
        ws32[OFF_FUD + g] = pkrtz(Wud[k0*32 + c],     Wud[(k0+1)*32 + c]);
        ws32[OFF_FK  + g] = pkrtz(Wk [k0*32 + c],     Wk [(k0+1)*32 + c]);
        ws32[OFF_FV  + g] = pkrtz(Wv [k0*32 + c],     Wv [(k0+1)*32 + c]);
        ws32[OFF_FQ  + g] = pkrtz(Wq [k0*32 + c]*isq, Wq [(k0+1)*32 + c]*isq);
        // fd1: input rows follow o's dword order: element 2p -> ch p, 2p+1 -> ch p+16
        ws32[OFF_FD1 + g] = pkrtz(Wd1[(k0>>1)*32 + c], Wd1[(16 + (k0>>1))*32 + c]);
        ws32[OFF_FD2 + g] = pkrtz(Wd2[k0*32 + c],     Wd2[(k0+1)*32 + c]);
    }
    if (g < 8704){
        int j = g >> 9, r = g & 511, t = r >> 8, rr = r & 255, lane = rr >> 2, i2 = rr & 3;
        int k0 = (lane>>4)*8 + 2*i2;
        int col = j*32 + (lane&15) + 16*t;
        ws32[OFF_FUP + g] = pkrtz(Wup[k0*544 + col], Wup[(k0+1)*544 + col]);
    }
}

// ---------------- fused kernel: 16 samples / block (4 waves) -----------------
// Phase1 (transposed MFMA) -> LDS. Phase2a (ALL 256 lanes = 128 pairs x 2
// key-halves): scores+softmax+PV with LDS merge. Phase2b: batched d1/d2 MFMAs.
__global__ __launch_bounds__(256,3)
void fused_kernel(const float* __restrict__ x, const unsigned* __restrict__ bmask,
                  const unsigned* __restrict__ ws32,
                  const float* __restrict__ bup, const float* __restrict__ bk,
                  const float* __restrict__ bv,  const float* __restrict__ bd1,
                  const float* __restrict__ bd2, const float* __restrict__ Ws,
                  const float* __restrict__ bs,  float* __restrict__ out, int B)
{
    __shared__ unsigned ksl[16*KSTRIDE];
    __shared__ unsigned vsl[16*KSTRIDE];
    __shared__ unsigned qsl[16*QSTRIDE];
    __shared__ unsigned usl[16*QSTRIDE];

    const int tid = threadIdx.x;
    const int wid = tid >> 6, wl = tid & 63;
    const int sb  = blockIdx.x * 16;
    const int s   = wl & 15, g4 = wl >> 4;
    const int smax = B - 1;

    // ---------------- phase 1 (round-10/13, verified) ----------------
    {
        int sA = sb + s; if (sA > smax) sA = smax;
        f16x8 ax;
        {
            const float* xr = x + (size_t)sA*34 + g4*8;
            float2 a0 = *(const float2*)(xr);
            float2 a1 = *(const float2*)(xr+2);
            float2 a2 = *(const float2*)(xr+4);
            float2 a3 = *(const float2*)(xr+6);
            uint4 u; u.x=pkrtz(a0.x,a0.y); u.y=pkrtz(a1.x,a1.y);
            u.z=pkrtz(a2.x,a2.y); u.w=pkrtz(a3.x,a3.y);
            ax = u4h8(u);
        }
        const unsigned bm = bmask[sA];
        float2 xt2 = *(const float2*)(x + (size_t)sA*34 + 32);
        const unsigned xtp = pkrtz(xt2.x, xt2.y);

        const uint4* wsu4 = (const uint4*)ws32;
        f16x8 fud0 = u4h8(wsu4[OFF_FUD/4 + wl]);
        f16x8 fud1 = u4h8(wsu4[OFF_FUD/4 + 64 + wl]);
        f16x8 fk0  = u4h8(wsu4[OFF_FK/4  + wl]);
        f16x8 fk1  = u4h8(wsu4[OFF_FK/4  + 64 + wl]);
        f16x8 fv0  = u4h8(wsu4[OFF_FV/4  + wl]);
        f16x8 fv1  = u4h8(wsu4[OFF_FV/4  + 64 + wl]);
        f16x8 fq0  = u4h8(wsu4[OFF_FQ/4  + wl]);
        f16x8 fq1  = u4h8(wsu4[OFF_FQ/4  + 64 + wl]);

        const float* ppf = (const float*)ws32;
        float4 bk0 = *(const float4*)(bk + g4*4);
        float4 bk1 = *(const float4*)(bk + 16 + g4*4);
        float4 bv0 = *(const float4*)(bv + g4*4);
        float4 bv1 = *(const float4*)(bv + 16 + g4*4);
        float4 bq0 = *(const float4*)(ppf + OFF_BQS + g4*4);
        float4 bq1 = *(const float4*)(ppf + OFF_BQS + 16 + g4*4);

        const int srcA = s + 32*(g4 & 1);
        const int srcB = srcA + 16;
        const bool selLo = (g4 < 2);

        const int njl = (wid == 3) ? 5 : 4;
        for (int jj = 0; jj < njl; jj++){
            const int j = (jj < 4) ? (wid + jj*4) : 16;
            f16x8 fup0 = u4h8(wsu4[OFF_FUP/4 + j*128 + wl]);
            f16x8 fup1 = u4h8(wsu4[OFF_FUP/4 + j*128 + 64 + wl]);
            float4 bu0 = *(const float4*)(bup + j*32 + g4*4);
            float4 bu1 = *(const float4*)(bup + j*32 + 16 + g4*4);
            float4 pp0 = *(const float4*)(ppf + OFF_PP + j*32 + g4*4);
            float4 pp1 = *(const float4*)(ppf + OFF_PP + j*32 + 16 + g4*4);
            uint4 tu0 = *(const uint4*)(ws32 + OFF_TUP + j*32 + g4*4);
            uint4 tu1 = *(const uint4*)(ws32 + OFF_TUP + j*32 + 16 + g4*4);

            f32x4 up0, up1;
            up0[0] = fdot2(xtp, tu0.x, bu0.x); up0[1] = fdot2(xtp, tu0.y, bu0.y);
            up0[2] = fdot2(xtp, tu0.z, bu0.z); up0[3] = fdot2(xtp, tu0.w, bu0.w);
            up1[0] = fdot2(xtp, tu1.x, bu1.x); up1[1] = fdot2(xtp, tu1.y, bu1.y);
            up1[2] = fdot2(xtp, tu1.z, bu1.z); up1[3] = fdot2(xtp, tu1.w, bu1.w);
            up0 = __builtin_amdgcn_mfma_f32_16x16x32_f16(fup0, ax, up0, 0,0,0);
            up1 = __builtin_amdgcn_mfma_f32_16x16x32_f16(fup1, ax, up1, 0,0,0);
            #pragma unroll
            for (int r=0;r<4;r++){ up0[r] = lrelu(up0[r]); up1[r] = lrelu(up1[r]); }

            const bool occ = !((bm>>j)&1u);
            const int rk = __popc((~bm) & ((1u<<j)-1u));
            if (occ){
                int rotq = (rk + s + (s>>2)) & 3;
                uint4 u;
                u.x = pkrtz(up0[0], up1[0]); u.y = pkrtz(up0[1], up1[1]);
                u.z = pkrtz(up0[2], up1[2]); u.w = pkrtz(up0[3], up1[3]);
                *(uint4*)&usl[s*QSTRIDE + rk*16 + ((g4 + rotq)&3)*4] = u;
            }
            f16x8 aup = repack(up0, up1, srcA, srcB, selLo);

            f32x4 uu0 = mk4(pp0), uu1 = mk4(pp1);
            uu0 = __builtin_amdgcn_mfma_f32_16x16x32_f16(fud0, aup, uu0, 0,0,0);
            uu1 = __builtin_amdgcn_mfma_f32_16x16x32_f16(fud1, aup, uu1, 0,0,0);
            #pragma unroll
            for (int r=0;r<4;r++){ uu0[r] = lrelu(uu0[r]); uu1[r] = lrelu(uu1[r]); }
            f16x8 auu = repack(uu0, uu1, srcA, srcB, selLo);

            f32x4 kk0 = mk4(bk0), kk1 = mk4(bk1);
            f32x4 vv0 = mk4(bv0), vv1 = mk4(bv1);
            f32x4 qq0 = mk4(bq0), qq1 = mk4(bq1);
            kk0 = __builtin_amdgcn_mfma_f32_16x16x32_f16(fk0, auu, kk0, 0,0,0);
            kk1 = __builtin_amdgcn_mfma_f32_16x16x32_f16(fk1, auu, kk1, 0,0,0);
            vv0 = __builtin_amdgcn_mfma_f32_16x16x32_f16(fv0, auu, vv0, 0,0,0);
            vv1 = __builtin_amdgcn_mfma_f32_16x16x32_f16(fv1, auu, vv1, 0,0,0);
            qq0 = __builtin_amdgcn_mfma_f32_16x16x32_f16(fq0, auu, qq0, 0,0,0);
            qq1 = __builtin_amdgcn_mfma_f32_16x16x32_f16(fq1, auu, qq1, 0,0,0);

            const int rot = (j + s + (s>>2)) & 3;
            const int grp = ((g4 + rot)&3)*4;
            uint4 kp, vp;
            kp.x = pkrtz(kk0[0], kk1[0]); kp.y = pkrtz(kk0[1], kk1[1]);
            kp.z = pkrtz(kk0[2], kk1[2]); kp.w = pkrtz(kk0[3], kk1[3]);
            vp.x = pkrtz(vv0[0], vv1[0]); vp.y = pkrtz(vv0[1], vv1[1]);
            vp.z = pkrtz(vv0[2], vv1[2]); vp.w = pkrtz(vv0[3], vv1[3]);
            *(uint4*)&ksl[s*KSTRIDE + j*16 + grp] = kp;
            *(uint4*)&vsl[s*KSTRIDE + j*16 + grp] = vp;
            if (occ){
                int rotq = (rk + s + (s>>2)) & 3;
                uint4 qp4;
                qp4.x = pkrtz(qq0[0], qq1[0]); qp4.y = pkrtz(qq0[1], qq1[1]);
                qp4.z = pkrtz(qq0[2], qq1[2]); qp4.w = pkrtz(qq0[3], qq1[3]);
                *(uint4*)&qsl[s*QSTRIDE + rk*16 + ((g4 + rotq)&3)*4] = qp4;
            }
        }
    }
    __syncthreads();

    // ---------------- phase 2a: ALL 256 lanes = 128 pairs x 2 key-halves ----
    const int half  = tid >> 7;           // wave-uniform: waves 0-1 / 2-3
    const int pr    = tid & 127;
    const int s2 = pr >> 3, q = pr & 7;
    const int kbase = half*8;             // half0: keys 0..8*, half1: keys 8..16
                                          // (*key 8 dup for scores; PV wt zeroed)
    unsigned qw[16];
    {
        int rot = (q + s2 + (s2>>2)) & 3;
        const unsigned* base = qsl + s2*QSTRIDE + q*16;
        #pragma unroll
        for (int a=0;a<4;a++){
            uint4 t = *(const uint4*)(base + ((a + rot)&3)*4);
            qw[4*a]=t.x; qw[4*a+1]=t.y; qw[4*a+2]=t.z; qw[4*a+3]=t.w;
        }
    }
    float scl[9];
    #pragma unroll
    for (int i=0;i<9;i++){
        int kj = kbase + i;
        unsigned kw[16];
        int rot = (kj + s2 + (s2>>2)) & 3;
        const unsigned* kb = ksl + s2*KSTRIDE + kj*16;
        #pragma unroll
        for (int a=0;a<4;a++){
            uint4 t = *(const uint4*)(kb + ((a + rot)&3)*4);
            kw[4*a]=t.x; kw[4*a+1]=t.y; kw[4*a+2]=t.z; kw[4*a+3]=t.w;
        }
        float s0=0.f,s1=0.f,s2a=0.f,s3=0.f;
        #pragma unroll
        for (int p=0;p<16;p+=4){
            s0  = fdot2(qw[p],   kw[p],   s0);
            s1  = fdot2(qw[p+1], kw[p+1], s1);
            s2a = fdot2(qw[p+2], kw[p+2], s2a);
            s3  = fdot2(qw[p+3], kw[p+3], s3);
        }
        scl[i] = (s0+s1)+(s2a+s3);
    }
    __syncthreads();                      // all k reads done -> ksl dead
    // scores -> ksl, stride 21 (coprime 32: conflict-free b32)
    #pragma unroll
    for (int i=0;i<9;i++) ksl[pr*21 + kbase + i] = __float_as_uint(scl[i]);
    __syncthreads();
    float sc[JN];
    #pragma unroll
    for (int kj=0;kj<JN;kj++) sc[kj] = __uint_as_float(ksl[pr*21 + kj]);
    float m = sc[0];
    #pragma unroll
    for (int kj=1;kj<JN;kj++) m = fmaxf(m, sc[kj]);
    float sum = 0.f;
    #pragma unroll
    for (int kj=0;kj<JN;kj++) sum += __expf(sc[kj]-m);
    float ri = 1.0f/sum;

    // PV over own keys only (o partial); half0's i==8 weight zeroed
    unsigned o[16];
    #pragma unroll
    for (int p=0;p<16;p++) o[p] = 0u;
    #pragma unroll
    for (int i=0;i<9;i++){
        int kj = kbase + i;
        float w = __expf(scl[i]-m)*ri;
        if (i==8 && half==0) w = 0.f;
        unsigned w2 = pkrtz(w, w);
        unsigned vw[16];
        int rot = (kj + s2 + (s2>>2)) & 3;
        const unsigned* vb = vsl + s2*KSTRIDE + kj*16;
        #pragma unroll
        for (int a=0;a<4;a++){
            uint4 t = *(const uint4*)(vb + ((a + rot)&3)*4);
            vw[4*a]=t.x; vw[4*a+1]=t.y; vw[4*a+2]=t.z; vw[4*a+3]=t.w;
        }
        #pragma unroll
        for (int p=0;p<16;p++) o[p] = pkfma(w2, vw[p], o[p]);
    }
    __syncthreads();                      // all v reads done -> vsl dead
    {
        int rot = (pr>>1)&3;
        unsigned* dst = vsl + half*2048 + pr*16;
        *(uint4*)&dst[((0+rot)&3)*4] = make_uint4(o[0],o[1],o[2],o[3]);
        *(uint4*)&dst[((1+rot)&3)*4] = make_uint4(o[4],o[5],o[6],o[7]);
        *(uint4*)&dst[((2+rot)&3)*4] = make_uint4(o[8],o[9],o[10],o[11]);
        *(uint4*)&dst[((3+rot)&3)*4] = make_uint4(o[12],o[13],o[14],o[15]);
    }
    __syncthreads();

    // ---------------- phase 2b: all 4 waves, d1/d2 as batched MFMAs ----------
    {
        const int rid = wl & 15, g4b = wl >> 4;
        const uint4* wsu4 = (const uint4*)ws32;
        f16x8 fd1_0 = u4h8(wsu4[OFF_FD1/4 + wl]);
        f16x8 fd1_1 = u4h8(wsu4[OFF_FD1/4 + 64 + wl]);
        f16x8 fd2_0 = u4h8(wsu4[OFF_FD2/4 + wl]);
        f16x8 fd2_1 = u4h8(wsu4[OFF_FD2/4 + 64 + wl]);
        float4 bd10 = *(const float4*)(bd1 + g4b*4);
        float4 bd11 = *(const float4*)(bd1 + 16 + g4b*4);
        float4 bd20 = *(const float4*)(bd2 + g4b*4);
        float4 bd21 = *(const float4*)(bd2 + 16 + g4b*4);
        float4 ws0  = *(const float4*)(Ws + g4b*4);
        float4 ws1  = *(const float4*)(Ws + 16 + g4b*4);
        const float bsv = bs[0];
        const int srcA = rid + 32*(g4b & 1);
        const int srcB = srcA + 16;
        const bool selLo = (g4b < 2);

        #pragma unroll
        for (int gg=0; gg<2; gg++){
            const int rowg = (wid*2 + gg)*16 + rid;       // 0..127
            int roto = (rowg>>1)&3;
            uint4 a4 = *(const uint4*)&vsl[rowg*16 + ((g4b + roto)&3)*4];
            uint4 b4 = *(const uint4*)&vsl[2048 + rowg*16 + ((g4b + roto)&3)*4];
            f16x8 bo = u4h8(a4) + u4h8(b4);               // merge o partials

            f32x4 t0 = mk4(bd10), t1 = mk4(bd11);
            t0 = __builtin_amdgcn_mfma_f32_16x16x32_f16(fd1_0, bo, t0, 0,0,0);
            t1 = __builtin_amdgcn_mfma_f32_16x16x32_f16(fd1_1, bo, t1, 0,0,0);
            #pragma unroll
            for (int r=0;r<4;r++){ t0[r] = lrelu(t0[r]); t1[r] = lrelu(t1[r]); }
            f16x8 bt = repack(t0, t1, srcA, srcB, selLo);

            const int s2b = rowg >> 3, qb = rowg & 7;
            int rotq = (qb + s2b + (s2b>>2)) & 3;
            uint4 ur = *(const uint4*)&usl[s2b*QSTRIDE + qb*16 + ((g4b + rotq)&3)*4];
            unsigned urr[4] = {ur.x, ur.y, ur.z, ur.w};
            f32x4 z0, z1;
            {
                h2v r0 = u2h(urr[0]), r1 = u2h(urr[1]), r2 = u2h(urr[2]), r3 = u2h(urr[3]);
                z0[0] = (float)r0.x + bd20.x; z1[0] = (float)r0.y + bd21.x;
                z0[1] = (float)r1.x + bd20.y; z1[1] = (float)r1.y + bd21.y;
                z0[2] = (float)r2.x + bd20.z; z1[2] = (float)r2.y + bd21.z;
                z0[3] = (float)r3.x + bd20.w; z1[3] = (float)r3.y + bd21.w;
            }
            z0 = __builtin_amdgcn_mfma_f32_16x16x32_f16(fd2_0, bt, z0, 0,0,0);
            z1 = __builtin_amdgcn_mfma_f32_16x16x32_f16(fd2_1, bt, z1, 0,0,0);

            float yp = z0[0]*ws0.x + z0[1]*ws0.y + z0[2]*ws0.z + z0[3]*ws0.w
                     + z1[0]*ws1.x + z1[1]*ws1.y + z1[2]*ws1.z + z1[3]*ws1.w;
            yp += __shfl_xor(yp, 16, 64);
            yp += __shfl_xor(yp, 32, 64);
            if (g4b == 0 && sb + s2b < B){
                float y = yp + bsv;
                out[((size_t)(sb + s2b))*8 + qb] = 1.0f/(1.0f + __expf(-y));
            }
        }
    }
}

extern "C" void kernel_launch(void* const* d_in, const int* in_sizes, int n_in,
                              void* d_out, int out_size, void* d_ws, size_t ws_size,
                              hipStream_t stream) {
    (void)n_in; (void)out_size; (void)ws_size;
    const float* x   = (const float*)d_in[0];
    const void*  m   = d_in[1];
    const float* pos = (const float*)d_in[2];
    const float* Wup = (const float*)d_in[3];  const float* bup = (const float*)d_in[4];
    const float* Wud = (const float*)d_in[5];  const float* bud = (const float*)d_in[6];
    const float* Wq  = (const float*)d_in[7];  const float* bq  = (const float*)d_in[8];
    const float* Wk  = (const float*)d_in[9];  const float* bk  = (const float*)d_in[10];
    const float* Wv  = (const float*)d_in[11]; const float* bv  = (const float*)d_in[12];
    const float* Wd1 = (const float*)d_in[13]; const float* bd1 = (const float*)d_in[14];
    const float* Wd2 = (const float*)d_in[15]; const float* bd2 = (const float*)d_in[16];
    const float* Ws  = (const float*)d_in[17]; const float* bs  = (const float*)d_in[18];
    float* out = (float*)d_out;
    int B = in_sizes[0] / (JN*2);

    unsigned char* wsb = (unsigned char*)d_ws;
    unsigned* ws32  = (unsigned*)wsb;
    unsigned* bmask = (unsigned*)(wsb + HDR_BYTES);

    prep_kernel<<<(B+255)/256, 256, 0, stream>>>(m, pos, Wup, Wud, bud, Wq, bq,
                                                 Wk, Wv, Wd1, Wd2, ws32, bmask, B);
    fused_kernel<<<(B+15)/16, 256, 0, stream>>>(x, bmask, ws32, bup, bk, bv,
                                                bd1, bd2, Ws, bs, out, B);
}